// Round 4
// baseline (125.659 us; speedup 1.0000x reference)
//
#include <hip/hip_runtime.h>
#include <math.h>

// Mecanum dynamics: per-row elementwise op, memory-bound (120 MB / launch,
// floor ~19 us @ 6.3 TB/s). 4 rows per thread -> ALL global traffic is
// float4 (16 B/lane): state 6x, ctrl 3x, out 6x per thread.
// Note: harness-timed window also contains ~93 us of d_ws poison + d_in
// restore fills (seen in rocprof as fillBufferAligned @41 us) we can't touch.

__device__ __forceinline__ void mecanum_row(
    float theta, float vx, float vy, float w,
    float u0, float u1, float u2,
    float& a0, float& a1, float& a2)
{
    // ---- compile-time constants (double math, cast to f32, matching numpy) ----
    constexpr double Gd   = 13.7;
    constexpr double LXd  = 0.129907;
    constexpr double LYd  = 0.095724;
    constexpr double Rd   = 3.0 * 0.0254;            // 0.0762
    constexpr double Kd   = LXd + LYd;               // 0.225631
    constexpr double MASSd = 12.0;
    constexpr double MOId = 12.0 * (12.0 * 0.0254) * (12.0 * 0.0254) / 6.0;

    const float Gf   = (float)Gd;
    const float invR = (float)(1.0 / Rd);            // LOCAL_TO_WHEEL_ROT +-1/R entries
    const float KoR  = (float)(Kd / Rd);             // +-(LX+LY)/R entries
    // pinv(local_to_wheel) closed form: MtM = diag(4,4,4k^2)
    //   row0 = [1,1,1,1]/4 ; row1 = [-1,1,1,-1]/4 ; row2 = [-1,1,-1,1]/(4k)
    const float s01  = (float)(0.25 / Rd / MASSd);
    const float s2   = (float)(1.0 / (4.0 * Kd) / Rd / MOId);

    float sn, cs;
    sincosf(theta, &sn, &cs);
    // A = rot(-theta): local_vel = A @ v
    const float lv0 = cs * vx + sn * vy;
    const float lv1 = cs * vy - sn * vx;

    // sign patterns shared by local_to_wheel cols 1,2 and CTRL_TO_MOTOR cols 1,2
    const float bw[4] = { -1.f, 1.f,  1.f, -1.f };
    const float fw[4] = { -1.f, 1.f, -1.f,  1.f };

    const float wvc0 = invR * lv0;
    const float wvc1 = invR * lv1;
    const float wvc2 = KoR * w;

    float wt_sum = 0.f, wt_b = 0.f, wt_f = 0.f;
#pragma unroll
    for (int i = 0; i < 4; ++i) {
        const float wv = wvc0 + bw[i] * wvc1 + fw[i] * wvc2;
        const float md = u0 + bw[i] * u1 + fw[i] * u2;
        const float ss = wv / sqrtf(wv * wv + 0.01f);           // softsign, eps=0.01
        const float wt = (md * 0.193f - (wv * Gf) * 0.000304f - ss * 0.00317f) * Gf;
        wt_sum += wt;
        wt_b   += bw[i] * wt;
        wt_f   += fw[i] * wt;
    }

    const float la0 = wt_sum * s01;
    const float la1 = wt_b   * s01;
    const float la2 = wt_f   * s2;

    // absolute_accel = A^T @ local_accel
    a0 = cs * la0 - sn * la1;
    a1 = sn * la0 + cs * la1;
    a2 = la2;
}

__global__ __launch_bounds__(256) void mecanum_kernel(
    const float* __restrict__ state,
    const float* __restrict__ ctrl,
    float* __restrict__ out,
    int nquads)
{
    const int tid = blockIdx.x * blockDim.x + threadIdx.x;
    if (tid >= nquads) return;

    const float4* __restrict__ s4 = (const float4*)state;
    const float4* __restrict__ c4 = (const float4*)ctrl;
    float4* __restrict__ o4 = (float4*)out;

    // 4 rows: state 24 floats = 6xfloat4, ctrl 12 floats = 3xfloat4
    float S[24];
#pragma unroll
    for (int k = 0; k < 6; ++k) {
        const float4 v = s4[6 * tid + k];
        S[4 * k + 0] = v.x; S[4 * k + 1] = v.y; S[4 * k + 2] = v.z; S[4 * k + 3] = v.w;
    }
    float U[12];
#pragma unroll
    for (int k = 0; k < 3; ++k) {
        const float4 v = c4[3 * tid + k];
        U[4 * k + 0] = v.x; U[4 * k + 1] = v.y; U[4 * k + 2] = v.z; U[4 * k + 3] = v.w;
    }

    float O[24];
#pragma unroll
    for (int r = 0; r < 4; ++r) {
        const float theta = S[6 * r + 2];
        const float vx = S[6 * r + 3], vy = S[6 * r + 4], w = S[6 * r + 5];
        float a0, a1, a2;
        mecanum_row(theta, vx, vy, w, U[3 * r + 0], U[3 * r + 1], U[3 * r + 2], a0, a1, a2);
        O[6 * r + 0] = vx; O[6 * r + 1] = vy; O[6 * r + 2] = w;
        O[6 * r + 3] = a0; O[6 * r + 4] = a1; O[6 * r + 5] = a2;
    }

#pragma unroll
    for (int k = 0; k < 6; ++k) {
        float4 v;
        v.x = O[4 * k + 0]; v.y = O[4 * k + 1]; v.z = O[4 * k + 2]; v.w = O[4 * k + 3];
        o4[6 * tid + k] = v;
    }
}

extern "C" void kernel_launch(void* const* d_in, const int* in_sizes, int n_in,
                              void* d_out, int out_size, void* d_ws, size_t ws_size,
                              hipStream_t stream) {
    // d_in[0] = t (unused, 1 elem), d_in[1] = state (B*6 f32), d_in[2] = control_duty (B*3 f32)
    const float* state = (const float*)d_in[1];
    const float* ctrl  = (const float*)d_in[2];
    float* out = (float*)d_out;

    const int B = in_sizes[1] / 6;          // 2,000,000
    const int nquads = B / 4;               // B divisible by 4
    const int block = 256;
    const int grid = (nquads + block - 1) / block;
    mecanum_kernel<<<grid, block, 0, stream>>>(state, ctrl, out, nquads);
}

// Round 6
// 117.679 us; speedup vs baseline: 1.0678x; 1.0678x over previous
//
#include <hip/hip_runtime.h>
#include <math.h>

// Mecanum dynamics: per-row elementwise op, memory-bound (120 MB / launch).
// 2 rows per thread -> global traffic is float4/float2 (16B/8B per lane),
// fully coalesced. Pure-BW floor ~19 us @ 6.3 TB/s.
// Measured round 3: total 118.8 us, of which ~93 us is harness d_ws-poison
// fills (rocprof: fillBufferAligned 2x41 us @ 81% HBM peak) + ~11 us d_in
// restore -> kernel slice ~25 us. Round 4's 4-rows/thread variant REGRESSED
// (+7 us): more live state / fewer waves, no BW to gain. Keep 2-row form.

__device__ __forceinline__ void mecanum_row(
    float theta, float vx, float vy, float w,
    float u0, float u1, float u2,
    float& a0, float& a1, float& a2)
{
    // ---- compile-time constants (double math, cast to f32, matching numpy) ----
    constexpr double Gd   = 13.7;
    constexpr double LXd  = 0.129907;
    constexpr double LYd  = 0.095724;
    constexpr double Rd   = 3.0 * 0.0254;            // 0.0762
    constexpr double Kd   = LXd + LYd;               // 0.225631
    constexpr double MASSd = 12.0;
    constexpr double MOId = 12.0 * (12.0 * 0.0254) * (12.0 * 0.0254) / 6.0;

    const float Gf   = (float)Gd;
    const float invR = (float)(1.0 / Rd);            // LOCAL_TO_WHEEL_ROT +-1/R entries
    const float KoR  = (float)(Kd / Rd);             // +-(LX+LY)/R entries
    // pinv(local_to_wheel) closed form: MtM = diag(4,4,4k^2)
    //   row0 = [1,1,1,1]/4 ; row1 = [-1,1,1,-1]/4 ; row2 = [-1,1,-1,1]/(4k)
    const float s01  = (float)(0.25 / Rd / MASSd);
    const float s2   = (float)(1.0 / (4.0 * Kd) / Rd / MOId);

    float sn, cs;
    sincosf(theta, &sn, &cs);
    // A = rot(-theta): local_vel = A @ v
    const float lv0 = cs * vx + sn * vy;
    const float lv1 = cs * vy - sn * vx;

    // sign patterns shared by local_to_wheel cols 1,2 and CTRL_TO_MOTOR cols 1,2
    const float bw[4] = { -1.f, 1.f,  1.f, -1.f };
    const float fw[4] = { -1.f, 1.f, -1.f,  1.f };

    const float wvc0 = invR * lv0;
    const float wvc1 = invR * lv1;
    const float wvc2 = KoR * w;

    float wt_sum = 0.f, wt_b = 0.f, wt_f = 0.f;
#pragma unroll
    for (int i = 0; i < 4; ++i) {
        const float wv = wvc0 + bw[i] * wvc1 + fw[i] * wvc2;
        const float md = u0 + bw[i] * u1 + fw[i] * u2;
        const float ss = wv / sqrtf(wv * wv + 0.01f);           // softsign, eps=0.01
        const float wt = (md * 0.193f - (wv * Gf) * 0.000304f - ss * 0.00317f) * Gf;
        wt_sum += wt;
        wt_b   += bw[i] * wt;
        wt_f   += fw[i] * wt;
    }

    const float la0 = wt_sum * s01;
    const float la1 = wt_b   * s01;
    const float la2 = wt_f   * s2;

    // absolute_accel = A^T @ local_accel
    a0 = cs * la0 - sn * la1;
    a1 = sn * la0 + cs * la1;
    a2 = la2;
}

__global__ __launch_bounds__(256) void mecanum_kernel(
    const float* __restrict__ state,
    const float* __restrict__ ctrl,
    float* __restrict__ out,
    int npairs)
{
    const int tid = blockIdx.x * blockDim.x + threadIdx.x;
    if (tid >= npairs) return;

    const float4* __restrict__ s4 = (const float4*)state;
    const float2* __restrict__ c2 = (const float2*)ctrl;
    float4* __restrict__ o4 = (float4*)out;

    const int base = 3 * tid;
    // two rows of state: 12 floats = 3 x float4
    const float4 sa = s4[base + 0];
    const float4 sb = s4[base + 1];
    const float4 sc = s4[base + 2];
    // two rows of ctrl: 6 floats = 3 x float2
    const float2 ca = c2[base + 0];
    const float2 cb = c2[base + 1];
    const float2 cc = c2[base + 2];

    // row 0: state = [sa.x sa.y sa.z sa.w sb.x sb.y], ctrl = [ca.x ca.y cb.x]
    float a00, a01, a02;
    mecanum_row(sa.z, sa.w, sb.x, sb.y, ca.x, ca.y, cb.x, a00, a01, a02);
    // row 1: state = [sb.z sb.w sc.x sc.y sc.z sc.w], ctrl = [cb.y cc.x cc.y]
    float a10, a11, a12;
    mecanum_row(sc.x, sc.y, sc.z, sc.w, cb.y, cc.x, cc.y, a10, a11, a12);

    // out rows: [vel(3), accel(3)] each -> 12 floats = 3 x float4
    float4 o0 = { sa.w, sb.x, sb.y, a00 };
    float4 o1 = { a01, a02, sc.y, sc.z };
    float4 o2 = { sc.w, a10, a11, a12 };
    o4[base + 0] = o0;
    o4[base + 1] = o1;
    o4[base + 2] = o2;
}

extern "C" void kernel_launch(void* const* d_in, const int* in_sizes, int n_in,
                              void* d_out, int out_size, void* d_ws, size_t ws_size,
                              hipStream_t stream) {
    // d_in[0] = t (unused, 1 elem), d_in[1] = state (B*6 f32), d_in[2] = control_duty (B*3 f32)
    const float* state = (const float*)d_in[1];
    const float* ctrl  = (const float*)d_in[2];
    float* out = (float*)d_out;

    const int B = in_sizes[1] / 6;          // 2,000,000
    const int npairs = B / 2;               // B is even
    const int block = 256;
    const int grid = (npairs + block - 1) / block;
    mecanum_kernel<<<grid, block, 0, stream>>>(state, ctrl, out, npairs);
}